// Round 8
// baseline (313.423 us; speedup 1.0000x reference)
//
#include <hip/hip_runtime.h>
#include <stdint.h>

typedef unsigned short u16;
typedef __attribute__((ext_vector_type(4))) float f32x4;
typedef __attribute__((ext_vector_type(8))) short bf16x8;
typedef __attribute__((ext_vector_type(4))) int i32x4;
typedef __attribute__((ext_vector_type(2))) unsigned int u32x2;

#define SEQ 4096
#define DIM 256
// scale = 1/sqrt(256) * log2(e), folded into Wq/bq so softmax uses raw exp2
#define QSCALE 0.09016844f

__device__ __forceinline__ u16 f2bf(float f) {
  union { float f; uint32_t u; } v; v.f = f;
  uint32_t r = (v.u + 0x7FFFu + ((v.u >> 16) & 1u)) >> 16;
  return (u16)r;
}

__device__ __forceinline__ void gload_lds16(const void* g, void* lds) {
  __builtin_amdgcn_global_load_lds(
      (const __attribute__((address_space(1))) uint32_t*)g,
      (__attribute__((address_space(3))) uint32_t*)lds, 16, 0, 0);
}

// ---------------- weight transpose + bf16 cast (scale folded for Wq) --------
__global__ __launch_bounds__(256) void wt_kernel(const float* __restrict__ Wq,
                                                 const float* __restrict__ Wk,
                                                 const float* __restrict__ Wv,
                                                 u16* __restrict__ wt) {
  int b = blockIdx.x;              // 0..767
  int w = b >> 8;                  // which matrix
  int n = b & 255;                 // output column -> wt row
  const float* W = (w == 0) ? Wq : ((w == 1) ? Wk : Wv);
  float scale = (w == 0) ? QSCALE : 1.0f;
  int k = threadIdx.x;
  wt[(w * 256 + n) * 256 + k] = f2bf(W[k * 256 + n] * scale);
}

// ---------------- QKV projection (verified round 1) --------------------------
__global__ __launch_bounds__(256) void qkv_kernel(
    const float* __restrict__ x, const float* __restrict__ bq,
    const float* __restrict__ bk, const float* __restrict__ bv,
    const u16* __restrict__ wt, u16* __restrict__ qs, u16* __restrict__ kk,
    char* __restrict__ vt) {
  __shared__ __align__(16) u16 lds_b[16384];
  __shared__ __align__(16) u16 lds_v[4096];
  int tid = threadIdx.x;
  int w = tid >> 6, l = tid & 63;
  int a = l & 15, g = l >> 4;
  int rowbase = blockIdx.x * 64;

  bf16x8 afr[8];
  {
    int row = rowbase + w * 16 + a;
    const float* xr = x + (size_t)row * 256;
#pragma unroll
    for (int ks = 0; ks < 8; ++ks) {
      int k0 = ks * 32 + g * 8;
      union { bf16x8 s; u16 u[8]; } fr;
#pragma unroll
      for (int i = 0; i < 8; ++i) fr.u[i] = f2bf(xr[k0 + i]);
      afr[ks] = fr.s;
    }
  }

  for (int w3 = 0; w3 < 3; ++w3) {
    const float* bias = (w3 == 0) ? bq : ((w3 == 1) ? bk : bv);
    for (int qn = 0; qn < 4; ++qn) {
      {
        const u16* src = wt + (w3 * 256 + qn * 64) * 256;
        for (int j = 0; j < 8; ++j) {
          uint32_t inst = w * 8 + j;
          uint32_t flat = inst * 1024 + l * 16;
          uint32_t row = flat >> 9;
          uint32_t c5 = (flat >> 4) & 31;
          uint32_t sc = (c5 & ~7u) | ((c5 ^ row) & 7u);
          gload_lds16(src + row * 256 + sc * 8, ((char*)lds_b) + inst * 1024);
        }
      }
      __syncthreads();
      f32x4 acc[4];
#pragma unroll
      for (int n0 = 0; n0 < 4; ++n0) acc[n0] = (f32x4){0.f, 0.f, 0.f, 0.f};
#pragma unroll
      for (int ks = 0; ks < 8; ++ks) {
#pragma unroll
        for (int n0 = 0; n0 < 4; ++n0) {
          uint32_t row = n0 * 16 + a;
          uint32_t c5 = ks * 4 + g;
          uint32_t sc = (c5 & ~7u) | ((c5 ^ row) & 7u);
          bf16x8 bfr = *(const bf16x8*)((const char*)lds_b + row * 512 + sc * 16);
          acc[n0] = __builtin_amdgcn_mfma_f32_16x16x32_bf16(afr[ks], bfr, acc[n0], 0, 0, 0);
        }
      }
      if (w3 < 2) {
        u16* out = (w3 == 0) ? qs : kk;
        float bscale = (w3 == 0) ? QSCALE : 1.0f;
#pragma unroll
        for (int n0 = 0; n0 < 4; ++n0) {
          int col = qn * 64 + n0 * 16 + a;
          float bb = bias[col] * bscale;
#pragma unroll
          for (int r = 0; r < 4; ++r) {
            int row = rowbase + w * 16 + g * 4 + r;
            out[(size_t)row * 256 + col] = f2bf(acc[n0][r] + bb);
          }
        }
      } else {
#pragma unroll
        for (int n0 = 0; n0 < 4; ++n0) {
          int col = qn * 64 + n0 * 16 + a;
          float bb = bias[col];
          int dl = n0 * 16 + a;
#pragma unroll
          for (int r = 0; r < 4; ++r) {
            int m = w * 16 + g * 4 + r;
            uint32_t byteoff =
                (uint32_t)dl * 128 + ((((uint32_t)m >> 3) ^ ((uint32_t)dl & 7)) << 4) + (m & 7) * 2;
            *(u16*)((char*)lds_v + byteoff) = f2bf(acc[n0][r] + bb);
          }
        }
        __syncthreads();
        {
          int dl = tid >> 2;
          size_t base = (size_t)blockIdx.x * 32768 + (size_t)(qn * 64 + dl) * 128;
#pragma unroll
          for (int cc = 0; cc < 2; ++cc) {
            uint32_t c = (tid & 3) + cc * 4;
            i32x4 vd = *(const i32x4*)((const char*)lds_v + dl * 128 + ((c ^ (dl & 7)) << 4));
            *(i32x4*)(vt + base + c * 16) = vd;
          }
        }
      }
      __syncthreads();
    }
  }
}

// ---------------- flash attention v8: wave-specialized, LDS only for P -------
// 8 waves: w0-3 = QK waves (kv-slice 16, all 64 q, Q in 128 VGPR);
//          w4-7 = PV waves (d-slice 64, all 64 q).
// K,V fragments load DIRECTLY global->VGPR from L2 (no LDS staging: slices are
// wave-disjoint, so staging added LDS write+read with zero sharing benefit).
// LDS holds only P: 64 rows x 160B (pad 128->160 spreads read banks), dbuf.
// Per tile: QK waves consume K(t), write P(t); PV waves consume P(t-1),V(t-1).
// One barrier per tile. Max-free softmax (exp2, scores pre-scaled by log2e/16);
// denominator via ones-MFMA on PV side.

#define QK_TILE(CUR, DO_K)                                                     \
  {                                                                            \
    f32x4 sc[4];                                                               \
    _Pragma("unroll") for (int mt = 0; mt < 4; ++mt)                           \
        sc[mt] = (f32x4){0.f, 0.f, 0.f, 0.f};                                  \
    __builtin_amdgcn_s_setprio(1);                                             \
    _Pragma("unroll") for (int ks = 0; ks < 8; ++ks) {                         \
      _Pragma("unroll") for (int mt = 0; mt < 4; ++mt)                         \
          sc[mt] = __builtin_amdgcn_mfma_f32_16x16x32_bf16(kfr[ks], qfr[mt][ks], \
                                                           sc[mt], 0, 0, 0);   \
    }                                                                          \
    __builtin_amdgcn_s_setprio(0);                                             \
    if (DO_K) {                                                                \
      _Pragma("unroll") for (int ks = 0; ks < 8; ++ks)                         \
          kfr[ks] = *(const bf16x8*)(kptr + ks * 64);                          \
      kptr += 32768;                                                           \
    }                                                                          \
    __builtin_amdgcn_sched_barrier(0);                                         \
    _Pragma("unroll") for (int mt = 0; mt < 4; ++mt) {                         \
      float e0 = exp2f(fminf(sc[mt][0], 43.f));                                \
      float e1 = exp2f(fminf(sc[mt][1], 43.f));                                \
      float e2 = exp2f(fminf(sc[mt][2], 43.f));                                \
      float e3 = exp2f(fminf(sc[mt][3], 43.f));                                \
      uint32_t p0 = (uint32_t)f2bf(e0) | ((uint32_t)f2bf(e1) << 16);           \
      uint32_t p1 = (uint32_t)f2bf(e2) | ((uint32_t)f2bf(e3) << 16);           \
      u32x2 pk = {p0, p1};                                                     \
      *(u32x2*)(lds + (CUR) * 10240 + pwo[mt]) = pk;                           \
    }                                                                          \
    asm volatile("s_waitcnt lgkmcnt(0)" ::: "memory");                         \
  }

#define PV_TILE(RSLOT)                                                         \
  {                                                                            \
    bf16x8 pfr[4][2];                                                          \
    _Pragma("unroll") for (int mt = 0; mt < 4; ++mt)                           \
    _Pragma("unroll") for (int kvw = 0; kvw < 2; ++kvw)                        \
        pfr[mt][kvw] =                                                         \
            *(const bf16x8*)(lds + (RSLOT) * 10240 + pro[mt * 2 + kvw]);       \
    __builtin_amdgcn_s_setprio(1);                                             \
    _Pragma("unroll") for (int mt = 0; mt < 4; ++mt)                           \
    _Pragma("unroll") for (int kvw = 0; kvw < 2; ++kvw)                        \
        lacc[mt] = __builtin_amdgcn_mfma_f32_16x16x32_bf16(pfr[mt][kvw], ones, \
                                                           lacc[mt], 0, 0, 0); \
    _Pragma("unroll") for (int d0 = 0; d0 < 4; ++d0)                           \
    _Pragma("unroll") for (int kvw = 0; kvw < 2; ++kvw) {                      \
      _Pragma("unroll") for (int mt = 0; mt < 4; ++mt)                         \
          o[mt][d0] = __builtin_amdgcn_mfma_f32_16x16x32_bf16(                 \
              pfr[mt][kvw], vfr[d0 * 2 + kvw], o[mt][d0], 0, 0, 0);            \
    }                                                                          \
    __builtin_amdgcn_s_setprio(0);                                             \
  }

#define PV_LOADV                                                               \
  {                                                                            \
    _Pragma("unroll") for (int d0 = 0; d0 < 4; ++d0)                           \
    _Pragma("unroll") for (int kvw = 0; kvw < 2; ++kvw)                        \
        vfr[d0 * 2 + kvw] = *(const bf16x8*)((d0 < 2 ? vp0 : vp1) +            \
                                             (d0 & 1) * 2048 + kvw * 64);      \
    vp0 += 32768;                                                              \
    vp1 += 32768;                                                              \
    __builtin_amdgcn_sched_barrier(0);                                         \
  }

#define BAR                                                                    \
  __builtin_amdgcn_s_barrier();                                                \
  __builtin_amdgcn_sched_barrier(0);

__global__ __launch_bounds__(512, 2) void attn_kernel(const u16* __restrict__ qs,
                                                      const u16* __restrict__ kk,
                                                      const char* __restrict__ vt,
                                                      float* __restrict__ out) {
  __shared__ __align__(16) char lds[20480];  // P dbuf: 2 x 64 rows x 160B
  int tid = threadIdx.x;
  int w = tid >> 6, l = tid & 63;
  int a = l & 15, g = l >> 4;
  bool isQK = (w < 4);
  int sub = w & 3;  // QK: kv-slice; PV: d-slice
  // XCD-bijective swizzle: batch -> XCD pair; 4MB KV set stays L2-resident
  int bx = blockIdx.x;
  int batch = (bx >> 1) & 3;
  int qt = ((bx >> 3) << 1) | (bx & 1);

  // P offsets (row stride 160B; granule XOR-swizzle ^ (a&7); read banks <=2-way)
  uint32_t pwo[4], pro[8];
#pragma unroll
  for (int mt = 0; mt < 4; ++mt) {
    uint32_t row = mt * 16 + a;
    pwo[mt] = row * 160 + ((((uint32_t)(sub * 2 + (g >> 1)) ^ (a & 7)) << 4) +
                           (g & 1) * 8);
#pragma unroll
    for (int kvw = 0; kvw < 2; ++kvw)
      pro[mt * 2 + kvw] = row * 160 + (((uint32_t)(kvw * 4 + g) ^ (a & 7)) << 4);
  }

  // per-role register state
  bf16x8 qfr[4][8];   // QK: Q[64q][256k] (pre-scaled), 128 VGPR
  bf16x8 kfr[8];      // QK: K fragment for its 16 kv rows
  bf16x8 vfr[8];      // PV: V^T fragment for its 64 d rows
  f32x4 o[4][4];      // PV: O[64q][64d]
  f32x4 lacc[4];      // PV: row-sums
  const short ob = (short)0x3F80;
  bf16x8 ones = {ob, ob, ob, ob, ob, ob, ob, ob};

  const char* kptr;
  const char* vp0;
  const char* vp1;

  if (isQK) {
    const u16* qp = qs + ((size_t)batch * SEQ + qt * 64) * 256;
#pragma unroll
    for (int mt = 0; mt < 4; ++mt)
#pragma unroll
      for (int ks = 0; ks < 8; ++ks)
        qfr[mt][ks] = *(const bf16x8*)(qp + (size_t)(mt * 16 + a) * 256 + ks * 32 + g * 8);
    // K(0): rows sub*16+a, bytes ks*64 + g*16
    kptr = (const char*)kk + (size_t)batch * SEQ * 512 + (size_t)(sub * 16 + a) * 512 + g * 16;
#pragma unroll
    for (int ks = 0; ks < 8; ++ks) kfr[ks] = *(const bf16x8*)(kptr + ks * 64);
    kptr += 32768;
  } else {
#pragma unroll
    for (int mt = 0; mt < 4; ++mt) {
      lacc[mt] = (f32x4){0.f, 0.f, 0.f, 0.f};
#pragma unroll
      for (int d0 = 0; d0 < 4; ++d0) o[mt][d0] = (f32x4){0.f, 0.f, 0.f, 0.f};
    }
    vp0 = vt + (size_t)batch * 64 * 32768 + (size_t)(sub * 64 + a) * 128 + g * 16;
    vp1 = vp0 + 4096;
  }

  // ---- t = 0 ----
  if (isQK) {
    QK_TILE(0, true)
  } else {
    PV_LOADV  // issue V(0)
  }
  BAR

  // ---- t = 1..62 (31 pairs) ----
  for (int tp = 0; tp < 31; ++tp) {
    if (isQK) {
      QK_TILE(1, true)
    } else {
      PV_TILE(0)
      PV_LOADV
    }
    BAR
    if (isQK) {
      QK_TILE(0, true)
    } else {
      PV_TILE(1)
      PV_LOADV
    }
    BAR
  }

  // ---- t = 63 ----
  if (isQK) {
    QK_TILE(1, false)
  } else {
    PV_TILE(0)
    PV_LOADV  // V(63)
  }
  BAR

  // ---- final: PV(63) + epilogue ----
  if (!isQK) {
    PV_TILE(1)
    float* op = out + ((size_t)batch * SEQ + (size_t)qt * 64) * 256 + sub * 64;
#pragma unroll
    for (int mt = 0; mt < 4; ++mt)
#pragma unroll
      for (int r = 0; r < 4; ++r) {
        float inv = 1.0f / lacc[mt][r];
        int q = mt * 16 + g * 4 + r;
#pragma unroll
        for (int d0 = 0; d0 < 4; ++d0)
          op[(size_t)q * 256 + d0 * 16 + a] = o[mt][d0][r] * inv;
      }
  }
}

extern "C" void kernel_launch(void* const* d_in, const int* in_sizes, int n_in,
                              void* d_out, int out_size, void* d_ws, size_t ws_size,
                              hipStream_t stream) {
  const float* x = (const float*)d_in[0];
  const float* Wq = (const float*)d_in[1];
  const float* bq = (const float*)d_in[2];
  const float* Wk = (const float*)d_in[3];
  const float* bk = (const float*)d_in[4];
  const float* Wv = (const float*)d_in[5];
  const float* bv = (const float*)d_in[6];
  char* ws = (char*)d_ws;
  u16* wt = (u16*)ws;                              // 3*256*256*2   = 0x60000
  u16* qs = (u16*)(ws + 0x60000);                  // 8MB
  u16* kk = (u16*)(ws + 0x60000 + 0x800000);       // 8MB
  char* vt = ws + 0x60000 + 0x1000000;             // 8MB
  wt_kernel<<<dim3(768), dim3(256), 0, stream>>>(Wq, Wk, Wv, wt);
  qkv_kernel<<<dim3(256), dim3(256), 0, stream>>>(x, bq, bk, bv, wt, qs, kk, vt);
  attn_kernel<<<dim3(256), dim3(512), 0, stream>>>(qs, kk, vt, (float*)d_out);
}

// Round 9
// 195.772 us; speedup vs baseline: 1.6010x; 1.6010x over previous
//
#include <hip/hip_runtime.h>
#include <stdint.h>

typedef unsigned short u16;
typedef __attribute__((ext_vector_type(4))) float f32x4;
typedef __attribute__((ext_vector_type(8))) short bf16x8;
typedef __attribute__((ext_vector_type(4))) int i32x4;
typedef __attribute__((ext_vector_type(2))) unsigned int u32x2;

#define SEQ 4096
#define DIM 256
// scale = 1/sqrt(256) * log2(e), folded into Wq/bq so softmax uses raw exp2
#define QSCALE 0.09016844f

__device__ __forceinline__ u16 f2bf(float f) {
  union { float f; uint32_t u; } v; v.f = f;
  uint32_t r = (v.u + 0x7FFFu + ((v.u >> 16) & 1u)) >> 16;
  return (u16)r;
}

__device__ __forceinline__ void gload_lds16(const void* g, void* lds) {
  __builtin_amdgcn_global_load_lds(
      (const __attribute__((address_space(1))) uint32_t*)g,
      (__attribute__((address_space(3))) uint32_t*)lds, 16, 0, 0);
}

// ---------------- weight transpose + bf16 cast (scale folded for Wq) --------
__global__ __launch_bounds__(256) void wt_kernel(const float* __restrict__ Wq,
                                                 const float* __restrict__ Wk,
                                                 const float* __restrict__ Wv,
                                                 u16* __restrict__ wt) {
  int b = blockIdx.x;              // 0..767
  int w = b >> 8;                  // which matrix
  int n = b & 255;                 // output column -> wt row
  const float* W = (w == 0) ? Wq : ((w == 1) ? Wk : Wv);
  float scale = (w == 0) ? QSCALE : 1.0f;
  int k = threadIdx.x;
  wt[(w * 256 + n) * 256 + k] = f2bf(W[k * 256 + n] * scale);
}

// ---------------- QKV projection (verified round 1) --------------------------
__global__ __launch_bounds__(256) void qkv_kernel(
    const float* __restrict__ x, const float* __restrict__ bq,
    const float* __restrict__ bk, const float* __restrict__ bv,
    const u16* __restrict__ wt, u16* __restrict__ qs, u16* __restrict__ kk,
    char* __restrict__ vt) {
  __shared__ __align__(16) u16 lds_b[16384];
  __shared__ __align__(16) u16 lds_v[4096];
  int tid = threadIdx.x;
  int w = tid >> 6, l = tid & 63;
  int a = l & 15, g = l >> 4;
  int rowbase = blockIdx.x * 64;

  bf16x8 afr[8];
  {
    int row = rowbase + w * 16 + a;
    const float* xr = x + (size_t)row * 256;
#pragma unroll
    for (int ks = 0; ks < 8; ++ks) {
      int k0 = ks * 32 + g * 8;
      union { bf16x8 s; u16 u[8]; } fr;
#pragma unroll
      for (int i = 0; i < 8; ++i) fr.u[i] = f2bf(xr[k0 + i]);
      afr[ks] = fr.s;
    }
  }

  for (int w3 = 0; w3 < 3; ++w3) {
    const float* bias = (w3 == 0) ? bq : ((w3 == 1) ? bk : bv);
    for (int qn = 0; qn < 4; ++qn) {
      {
        const u16* src = wt + (w3 * 256 + qn * 64) * 256;
        for (int j = 0; j < 8; ++j) {
          uint32_t inst = w * 8 + j;
          uint32_t flat = inst * 1024 + l * 16;
          uint32_t row = flat >> 9;
          uint32_t c5 = (flat >> 4) & 31;
          uint32_t sc = (c5 & ~7u) | ((c5 ^ row) & 7u);
          gload_lds16(src + row * 256 + sc * 8, ((char*)lds_b) + inst * 1024);
        }
      }
      __syncthreads();
      f32x4 acc[4];
#pragma unroll
      for (int n0 = 0; n0 < 4; ++n0) acc[n0] = (f32x4){0.f, 0.f, 0.f, 0.f};
#pragma unroll
      for (int ks = 0; ks < 8; ++ks) {
#pragma unroll
        for (int n0 = 0; n0 < 4; ++n0) {
          uint32_t row = n0 * 16 + a;
          uint32_t c5 = ks * 4 + g;
          uint32_t sc = (c5 & ~7u) | ((c5 ^ row) & 7u);
          bf16x8 bfr = *(const bf16x8*)((const char*)lds_b + row * 512 + sc * 16);
          acc[n0] = __builtin_amdgcn_mfma_f32_16x16x32_bf16(afr[ks], bfr, acc[n0], 0, 0, 0);
        }
      }
      if (w3 < 2) {
        u16* out = (w3 == 0) ? qs : kk;
        float bscale = (w3 == 0) ? QSCALE : 1.0f;
#pragma unroll
        for (int n0 = 0; n0 < 4; ++n0) {
          int col = qn * 64 + n0 * 16 + a;
          float bb = bias[col] * bscale;
#pragma unroll
          for (int r = 0; r < 4; ++r) {
            int row = rowbase + w * 16 + g * 4 + r;
            out[(size_t)row * 256 + col] = f2bf(acc[n0][r] + bb);
          }
        }
      } else {
#pragma unroll
        for (int n0 = 0; n0 < 4; ++n0) {
          int col = qn * 64 + n0 * 16 + a;
          float bb = bias[col];
          int dl = n0 * 16 + a;
#pragma unroll
          for (int r = 0; r < 4; ++r) {
            int m = w * 16 + g * 4 + r;
            uint32_t byteoff =
                (uint32_t)dl * 128 + ((((uint32_t)m >> 3) ^ ((uint32_t)dl & 7)) << 4) + (m & 7) * 2;
            *(u16*)((char*)lds_v + byteoff) = f2bf(acc[n0][r] + bb);
          }
        }
        __syncthreads();
        {
          int dl = tid >> 2;
          size_t base = (size_t)blockIdx.x * 32768 + (size_t)(qn * 64 + dl) * 128;
#pragma unroll
          for (int cc = 0; cc < 2; ++cc) {
            uint32_t c = (tid & 3) + cc * 4;
            i32x4 vd = *(const i32x4*)((const char*)lds_v + dl * 128 + ((c ^ (dl & 7)) << 4));
            *(i32x4*)(vt + base + c * 16) = vd;
          }
        }
      }
      __syncthreads();
    }
  }
}

// ---------------- flash attention v9: v7 minus LDS-V (V direct to VGPR) ------
// LDS: [0,64K) K dbuf | [64K,80K) P dbuf (2 x 8K).
// V has zero inter-wave sharing per (qh,sub) d-slice -> no LDS staging; V(t-1)
// loads issue global->VGPR right after the tile-top barrier (~700cy before PV
// use). K stays LDS-staged (shared by the 2 q-half waves). Single barrier/tile.
// Max-free softmax (exp2, scores pre-scaled); denominator via ones-MFMA.
__device__ __forceinline__ void stage4(const char* src, char* ldsbase,
                                       const uint32_t* so, int w) {
#pragma unroll
  for (int j = 0; j < 4; ++j)
    gload_lds16(src + so[j], ldsbase + (w * 4 + j) * 1024);
}

#define PV_STEP(SLOT)                                                          \
  {                                                                            \
    bf16x8 pfr[2][2];                                                          \
    _Pragma("unroll") for (int mt = 0; mt < 2; ++mt)                           \
    _Pragma("unroll") for (int ks2 = 0; ks2 < 2; ++ks2)                        \
        pfr[mt][ks2] = *(const bf16x8*)(lds + (SLOT) * 8192 + pro[mt * 2 + ks2]); \
    __builtin_amdgcn_s_setprio(1);                                             \
    _Pragma("unroll") for (int mt = 0; mt < 2; ++mt)                           \
    _Pragma("unroll") for (int ks2 = 0; ks2 < 2; ++ks2)                        \
        lacc[mt] = __builtin_amdgcn_mfma_f32_16x16x32_bf16(pfr[mt][ks2], ones, \
                                                           lacc[mt], 0, 0, 0); \
    _Pragma("unroll") for (int d0 = 0; d0 < 4; ++d0)                           \
    _Pragma("unroll") for (int ks2 = 0; ks2 < 2; ++ks2) {                      \
      _Pragma("unroll") for (int mt = 0; mt < 2; ++mt)                         \
          o[mt][d0] = __builtin_amdgcn_mfma_f32_16x16x32_bf16(                 \
              pfr[mt][ks2], vfr[d0 * 2 + ks2], o[mt][d0], 0, 0, 0);            \
    }                                                                          \
    __builtin_amdgcn_s_setprio(0);                                             \
  }

#define LOADV                                                                  \
  {                                                                            \
    _Pragma("unroll") for (int d0 = 0; d0 < 4; ++d0)                           \
    _Pragma("unroll") for (int ks2 = 0; ks2 < 2; ++ks2)                        \
        vfr[d0 * 2 + ks2] = *(const bf16x8*)((d0 < 2 ? vp0 : vp1) +            \
                                             (d0 & 1) * 2048 + ks2 * 64);      \
    vp0 += 32768;                                                              \
    vp1 += 32768;                                                              \
  }

#define TILE(CUR, DO_PV, DO_K)                                                 \
  {                                                                            \
    asm volatile("s_waitcnt vmcnt(0) lgkmcnt(0)" ::: "memory");                \
    __builtin_amdgcn_s_barrier();                                              \
    __builtin_amdgcn_sched_barrier(0);                                         \
    if (DO_PV) LOADV                            /* V(t-1) -> vfr, used below */\
    if (DO_K) stage4(kstp, lds + ((CUR) ^ 1) * 32768, kso, w);                 \
    kstp += 32768;                                                             \
    f32x4 sc0 = {0.f, 0.f, 0.f, 0.f}, sc1 = {0.f, 0.f, 0.f, 0.f};              \
    __builtin_amdgcn_s_setprio(1);                                             \
    _Pragma("unroll") for (int ks = 0; ks < 8; ++ks) {                         \
      bf16x8 kfr = *(const bf16x8*)(lds + (CUR) * 32768 + kro[ks]);            \
      sc0 = __builtin_amdgcn_mfma_f32_16x16x32_bf16(kfr, qfr[0][ks], sc0, 0, 0, 0); \
      sc1 = __builtin_amdgcn_mfma_f32_16x16x32_bf16(kfr, qfr[1][ks], sc1, 0, 0, 0); \
    }                                                                          \
    __builtin_amdgcn_s_setprio(0);                                             \
    _Pragma("unroll") for (int mt = 0; mt < 2; ++mt) {                         \
      f32x4 s = mt ? sc1 : sc0;                                                \
      float e0 = exp2f(fminf(s[0], 43.f));                                     \
      float e1 = exp2f(fminf(s[1], 43.f));                                     \
      float e2 = exp2f(fminf(s[2], 43.f));                                     \
      float e3 = exp2f(fminf(s[3], 43.f));                                     \
      uint32_t p0 = (uint32_t)f2bf(e0) | ((uint32_t)f2bf(e1) << 16);           \
      uint32_t p1 = (uint32_t)f2bf(e2) | ((uint32_t)f2bf(e3) << 16);           \
      u32x2 pk = {p0, p1};                                                     \
      *(u32x2*)(lds + (CUR) * 8192 + pwo[mt]) = pk;                            \
    }                                                                          \
    if (DO_PV) PV_STEP((CUR) ^ 1)                                              \
  }

__global__ __launch_bounds__(512, 1) void attn_kernel(const u16* __restrict__ qs,
                                                      const u16* __restrict__ kk,
                                                      const char* __restrict__ vt,
                                                      float* __restrict__ out) {
  __shared__ __align__(16) char lds[81920];
  int tid = threadIdx.x;
  int w = tid >> 6, l = tid & 63;
  int a = l & 15, g = l >> 4;
  int qh = w >> 2, sub = w & 3;
  // XCD-bijective swizzle: batch -> XCD pair; 4MB KV set stays L2-resident
  int bx = blockIdx.x;
  int batch = (bx >> 1) & 3;
  int qt = ((bx >> 3) << 1) | (bx & 1);

  // ---- precomputed LDS byte offsets (swizzles baked; P base = 64K) ---------
  uint32_t kro[8], pro[4], pwo[2], kso[4];
#pragma unroll
  for (int ks = 0; ks < 8; ++ks) {
    uint32_t row = sub * 16 + a, c5 = ks * 4 + g;
    kro[ks] = row * 512 + (((c5 & ~7u) | ((c5 ^ row) & 7u)) << 4);
  }
#pragma unroll
  for (int mt = 0; mt < 2; ++mt) {
    uint32_t q = qh * 32 + mt * 16 + a;
#pragma unroll
    for (int ks2 = 0; ks2 < 2; ++ks2) {
      uint32_t c4 = ks2 * 4 + g;
      pro[mt * 2 + ks2] = 65536u + q * 128 + ((c4 ^ (q & 7)) << 4);
    }
    uint32_t c4w = sub * 2 + (g >> 1);
    pwo[mt] = 65536u + q * 128 + ((c4w ^ (q & 7)) << 4) + (g & 1) * 8;
  }
#pragma unroll
  for (int j = 0; j < 4; ++j) {
    uint32_t inst = w * 4 + j, flat = inst * 1024 + l * 16;
    uint32_t row = flat >> 9, c5 = (flat >> 4) & 31;
    kso[j] = row * 512 + (((c5 & ~7u) | ((c5 ^ row) & 7u)) << 4);
  }

  // Q fragments for 32 q-rows (pre-scaled by log2e/16); valid B-operand layout
  bf16x8 qfr[2][8];
  {
    const u16* qp = qs + ((size_t)batch * SEQ + qt * 64 + qh * 32) * 256;
#pragma unroll
    for (int mt = 0; mt < 2; ++mt)
#pragma unroll
      for (int ks = 0; ks < 8; ++ks)
        qfr[mt][ks] = *(const bf16x8*)(qp + (size_t)(mt * 16 + a) * 256 + ks * 32 + g * 8);
  }

  f32x4 o[2][4];   // O[32q][64d] (d-slice sub)
  f32x4 lacc[2];   // row-sums of P
  bf16x8 vfr[8];   // V(t-1) fragments, direct from global (L2)
#pragma unroll
  for (int mt = 0; mt < 2; ++mt) {
    lacc[mt] = (f32x4){0.f, 0.f, 0.f, 0.f};
#pragma unroll
    for (int d0 = 0; d0 < 4; ++d0) o[mt][d0] = (f32x4){0.f, 0.f, 0.f, 0.f};
  }
  const short ob = (short)0x3F80;  // bf16 1.0
  bf16x8 ones = {ob, ob, ob, ob, ob, ob, ob, ob};

  const char* kbase = (const char*)kk + (size_t)batch * SEQ * 512;
  const char* kstp = kbase + 32768;  // K(t+1) source
  // V per-lane bases: rows sub*64 + {0,1|2,3}*16 + a, byte in row = ks2*64+g*16
  const char* vp0 = vt + (size_t)batch * 64 * 32768 + (size_t)(sub * 64 + a) * 128 + g * 16;
  const char* vp1 = vp0 + 4096;

  // prologue: stage K(0) into slot 0
  stage4(kbase, lds, kso, w);

  TILE(0, false, true)                       // t = 0
  for (int tp = 0; tp < 31; ++tp) {          // t = 1..62
    TILE(1, true, true)
    TILE(0, true, true)
  }
  TILE(1, true, false)                       // t = 63 (no K(64) stage)

  // ---- epilogue: load V(63), PV(63), normalize + store --------------------
  asm volatile("s_waitcnt lgkmcnt(0)" ::: "memory");
  __builtin_amdgcn_s_barrier();
  __builtin_amdgcn_sched_barrier(0);
  LOADV  // V(63)
  PV_STEP(1)

  float* op = out + ((size_t)batch * SEQ + (size_t)qt * 64 + qh * 32) * 256 + sub * 64;
#pragma unroll
  for (int mt = 0; mt < 2; ++mt)
#pragma unroll
    for (int r = 0; r < 4; ++r) {
      float inv = 1.0f / lacc[mt][r];
#pragma unroll
      for (int d0 = 0; d0 < 4; ++d0)
        op[(size_t)(mt * 16 + g * 4 + r) * 256 + d0 * 16 + a] = o[mt][d0][r] * inv;
    }
}

extern "C" void kernel_launch(void* const* d_in, const int* in_sizes, int n_in,
                              void* d_out, int out_size, void* d_ws, size_t ws_size,
                              hipStream_t stream) {
  const float* x = (const float*)d_in[0];
  const float* Wq = (const float*)d_in[1];
  const float* bq = (const float*)d_in[2];
  const float* Wk = (const float*)d_in[3];
  const float* bk = (const float*)d_in[4];
  const float* Wv = (const float*)d_in[5];
  const float* bv = (const float*)d_in[6];
  char* ws = (char*)d_ws;
  u16* wt = (u16*)ws;                              // 3*256*256*2   = 0x60000
  u16* qs = (u16*)(ws + 0x60000);                  // 8MB
  u16* kk = (u16*)(ws + 0x60000 + 0x800000);       // 8MB
  char* vt = ws + 0x60000 + 0x1000000;             // 8MB
  wt_kernel<<<dim3(768), dim3(256), 0, stream>>>(Wq, Wk, Wv, wt);
  qkv_kernel<<<dim3(256), dim3(256), 0, stream>>>(x, bq, bk, bv, wt, qs, kk, vt);
  attn_kernel<<<dim3(256), dim3(512), 0, stream>>>(qs, kk, vt, (float*)d_out);
}

// Round 11
// 131.437 us; speedup vs baseline: 2.3846x; 1.4895x over previous
//
#include <hip/hip_runtime.h>
#include <stdint.h>

typedef unsigned short u16;
typedef __attribute__((ext_vector_type(4))) float f32x4;
typedef __attribute__((ext_vector_type(8))) short bf16x8;
typedef __attribute__((ext_vector_type(4))) int i32x4;
typedef __attribute__((ext_vector_type(2))) unsigned int u32x2;

#define SEQ 4096
#define DIM 256
// scale = 1/sqrt(256) * log2(e), folded into Wq/bq so softmax uses raw exp2
#define QSCALE 0.09016844f

__device__ __forceinline__ u16 f2bf(float f) {
  union { float f; uint32_t u; } v; v.f = f;
  uint32_t r = (v.u + 0x7FFFu + ((v.u >> 16) & 1u)) >> 16;
  return (u16)r;
}

__device__ __forceinline__ void gload_lds16(const void* g, void* lds) {
  __builtin_amdgcn_global_load_lds(
      (const __attribute__((address_space(1))) uint32_t*)g,
      (__attribute__((address_space(3))) uint32_t*)lds, 16, 0, 0);
}

// ---------------- weight transpose + bf16 cast (scale folded for Wq) --------
__global__ __launch_bounds__(256) void wt_kernel(const float* __restrict__ Wq,
                                                 const float* __restrict__ Wk,
                                                 const float* __restrict__ Wv,
                                                 u16* __restrict__ wt) {
  int b = blockIdx.x;              // 0..767
  int w = b >> 8;                  // which matrix
  int n = b & 255;                 // output column -> wt row
  const float* W = (w == 0) ? Wq : ((w == 1) ? Wk : Wv);
  float scale = (w == 0) ? QSCALE : 1.0f;
  int k = threadIdx.x;
  wt[(w * 256 + n) * 256 + k] = f2bf(W[k * 256 + n] * scale);
}

// ---------------- QKV projection (verified round 1) --------------------------
__global__ __launch_bounds__(256) void qkv_kernel(
    const float* __restrict__ x, const float* __restrict__ bq,
    const float* __restrict__ bk, const float* __restrict__ bv,
    const u16* __restrict__ wt, u16* __restrict__ qs, u16* __restrict__ kk,
    char* __restrict__ vt) {
  __shared__ __align__(16) u16 lds_b[16384];
  __shared__ __align__(16) u16 lds_v[4096];
  int tid = threadIdx.x;
  int w = tid >> 6, l = tid & 63;
  int a = l & 15, g = l >> 4;
  int rowbase = blockIdx.x * 64;

  bf16x8 afr[8];
  {
    int row = rowbase + w * 16 + a;
    const float* xr = x + (size_t)row * 256;
#pragma unroll
    for (int ks = 0; ks < 8; ++ks) {
      int k0 = ks * 32 + g * 8;
      union { bf16x8 s; u16 u[8]; } fr;
#pragma unroll
      for (int i = 0; i < 8; ++i) fr.u[i] = f2bf(xr[k0 + i]);
      afr[ks] = fr.s;
    }
  }

  for (int w3 = 0; w3 < 3; ++w3) {
    const float* bias = (w3 == 0) ? bq : ((w3 == 1) ? bk : bv);
    for (int qn = 0; qn < 4; ++qn) {
      {
        const u16* src = wt + (w3 * 256 + qn * 64) * 256;
        for (int j = 0; j < 8; ++j) {
          uint32_t inst = w * 8 + j;
          uint32_t flat = inst * 1024 + l * 16;
          uint32_t row = flat >> 9;
          uint32_t c5 = (flat >> 4) & 31;
          uint32_t sc = (c5 & ~7u) | ((c5 ^ row) & 7u);
          gload_lds16(src + row * 256 + sc * 8, ((char*)lds_b) + inst * 1024);
        }
      }
      __syncthreads();
      f32x4 acc[4];
#pragma unroll
      for (int n0 = 0; n0 < 4; ++n0) acc[n0] = (f32x4){0.f, 0.f, 0.f, 0.f};
#pragma unroll
      for (int ks = 0; ks < 8; ++ks) {
#pragma unroll
        for (int n0 = 0; n0 < 4; ++n0) {
          uint32_t row = n0 * 16 + a;
          uint32_t c5 = ks * 4 + g;
          uint32_t sc = (c5 & ~7u) | ((c5 ^ row) & 7u);
          bf16x8 bfr = *(const bf16x8*)((const char*)lds_b + row * 512 + sc * 16);
          acc[n0] = __builtin_amdgcn_mfma_f32_16x16x32_bf16(afr[ks], bfr, acc[n0], 0, 0, 0);
        }
      }
      if (w3 < 2) {
        u16* out = (w3 == 0) ? qs : kk;
        float bscale = (w3 == 0) ? QSCALE : 1.0f;
#pragma unroll
        for (int n0 = 0; n0 < 4; ++n0) {
          int col = qn * 64 + n0 * 16 + a;
          float bb = bias[col] * bscale;
#pragma unroll
          for (int r = 0; r < 4; ++r) {
            int row = rowbase + w * 16 + g * 4 + r;
            out[(size_t)row * 256 + col] = f2bf(acc[n0][r] + bb);
          }
        }
      } else {
#pragma unroll
        for (int n0 = 0; n0 < 4; ++n0) {
          int col = qn * 64 + n0 * 16 + a;
          float bb = bias[col];
          int dl = n0 * 16 + a;
#pragma unroll
          for (int r = 0; r < 4; ++r) {
            int m = w * 16 + g * 4 + r;
            uint32_t byteoff =
                (uint32_t)dl * 128 + ((((uint32_t)m >> 3) ^ ((uint32_t)dl & 7)) << 4) + (m & 7) * 2;
            *(u16*)((char*)lds_v + byteoff) = f2bf(acc[n0][r] + bb);
          }
        }
        __syncthreads();
        {
          int dl = tid >> 2;
          size_t base = (size_t)blockIdx.x * 32768 + (size_t)(qn * 64 + dl) * 128;
#pragma unroll
          for (int cc = 0; cc < 2; ++cc) {
            uint32_t c = (tid & 3) + cc * 4;
            i32x4 vd = *(const i32x4*)((const char*)lds_v + dl * 128 + ((c ^ (dl & 7)) << 4));
            *(i32x4*)(vt + base + c * 16) = vd;
          }
        }
      }
      __syncthreads();
    }
  }
}

// ---------------- flash attention v11: QBLK=128, kv-split, v7 swizzles -------
// VMEM-traffic law (v7 vs v9): tile time ~ VMEM bytes / (~16 B/cy/CU). Block =
// (batch, qt in 32, kv-half h): 128 q x 2048 kv; KV tile staged once serves 2x
// the q-rows of v7. Max-free softmax is LINEAR over kv: partial (O,l) add;
// h=0 -> d_out, h=1 -> ws; combine = (OA+OB)/(lA+lB).
// All LDS offsets use the VERIFIED v7 scheme: per-fragment hoisted offsets,
// full 3-bit row XOR on both sides, lane-UNIFORM global chunk per MFMA (round
// 10's folded per-lane permutation violated MFMA k-window uniformity).
// Sub-tile steps are compile-time immediates: K n-step 8192, P mt-step 2048,
// V d0-step 2048. LDS 144K: K dbuf 2x32K | V dbuf 2x32K | P 16K (single).
// Waves (qq = w>>1, sub = w&1): QK 32q x 32kv; PV 32q x 128d over 64 kv.
__device__ __forceinline__ void stage4(const char* src, char* ldsbase,
                                       const uint32_t* so, int w) {
#pragma unroll
  for (int j = 0; j < 4; ++j)
    gload_lds16(src + so[j], ldsbase + (w * 4 + j) * 1024);
}

#define TILE(CUR)                                                              \
  {                                                                            \
    asm volatile("s_waitcnt vmcnt(0) lgkmcnt(0)" ::: "memory");                \
    __builtin_amdgcn_s_barrier();                                              \
    __builtin_amdgcn_sched_barrier(0);                                         \
    if (tcur + 1 < nt) {                                                       \
      stage4(kstp, lds + ((CUR) ^ 1) * 32768, kso, w);                         \
      stage4(vstp, lds + 65536 + ((CUR) ^ 1) * 32768, vso, w);                 \
    }                                                                          \
    kstp += 32768;                                                             \
    vstp += 32768;                                                             \
    f32x4 sc[2][2];                                                            \
    _Pragma("unroll") for (int mt = 0; mt < 2; ++mt)                           \
    _Pragma("unroll") for (int n = 0; n < 2; ++n)                              \
        sc[mt][n] = (f32x4){0.f, 0.f, 0.f, 0.f};                               \
    __builtin_amdgcn_s_setprio(1);                                             \
    _Pragma("unroll") for (int n = 0; n < 2; ++n)                              \
    _Pragma("unroll") for (int j = 0; j < 8; ++j) {                            \
      bf16x8 kfr = *(const bf16x8*)(lds + (CUR) * 32768 + kro[j] + n * 8192);  \
      sc[0][n] = __builtin_amdgcn_mfma_f32_16x16x32_bf16(kfr, qfr[0][j], sc[0][n], 0, 0, 0); \
      sc[1][n] = __builtin_amdgcn_mfma_f32_16x16x32_bf16(kfr, qfr[1][j], sc[1][n], 0, 0, 0); \
    }                                                                          \
    __builtin_amdgcn_s_setprio(0);                                             \
    _Pragma("unroll") for (int mt = 0; mt < 2; ++mt)                           \
    _Pragma("unroll") for (int n = 0; n < 2; ++n) {                            \
      float e0 = exp2f(fminf(sc[mt][n][0], 43.f));                             \
      float e1 = exp2f(fminf(sc[mt][n][1], 43.f));                             \
      float e2 = exp2f(fminf(sc[mt][n][2], 43.f));                             \
      float e3 = exp2f(fminf(sc[mt][n][3], 43.f));                             \
      uint32_t p0 = (uint32_t)f2bf(e0) | ((uint32_t)f2bf(e1) << 16);           \
      uint32_t p1 = (uint32_t)f2bf(e2) | ((uint32_t)f2bf(e3) << 16);           \
      u32x2 pk = {p0, p1};                                                     \
      *(u32x2*)(lds + pwo[n] + mt * 2048) = pk;                                \
    }                                                                          \
    asm volatile("s_waitcnt lgkmcnt(0)" ::: "memory");                         \
    __builtin_amdgcn_s_barrier();                                              \
    __builtin_amdgcn_sched_barrier(0);                                         \
    bf16x8 pfr[2][2];                                                          \
    _Pragma("unroll") for (int mt = 0; mt < 2; ++mt)                           \
    _Pragma("unroll") for (int j2 = 0; j2 < 2; ++j2)                           \
        pfr[mt][j2] = *(const bf16x8*)(lds + pro[j2] + mt * 2048);             \
    __builtin_amdgcn_s_setprio(1);                                             \
    _Pragma("unroll") for (int mt = 0; mt < 2; ++mt)                           \
    _Pragma("unroll") for (int j2 = 0; j2 < 2; ++j2)                           \
        lacc[mt] = __builtin_amdgcn_mfma_f32_16x16x32_bf16(pfr[mt][j2], ones,  \
                                                           lacc[mt], 0, 0, 0); \
    _Pragma("unroll") for (int d0 = 0; d0 < 8; ++d0)                           \
    _Pragma("unroll") for (int j2 = 0; j2 < 2; ++j2) {                         \
      bf16x8 vfr = *(const bf16x8*)(lds + 65536 + (CUR) * 32768 + vro[j2] +    \
                                    d0 * 2048);                                \
      o[0][d0] = __builtin_amdgcn_mfma_f32_16x16x32_bf16(pfr[0][j2], vfr, o[0][d0], 0, 0, 0); \
      o[1][d0] = __builtin_amdgcn_mfma_f32_16x16x32_bf16(pfr[1][j2], vfr, o[1][d0], 0, 0, 0); \
    }                                                                          \
    __builtin_amdgcn_s_setprio(0);                                             \
    ++tcur;                                                                    \
  }

__global__ __launch_bounds__(512, 1) void attn_kernel(
    const u16* __restrict__ qs, const u16* __restrict__ kk,
    const char* __restrict__ vt, float* __restrict__ out,
    float* __restrict__ pOB, float* __restrict__ pl, int split) {
  __shared__ __align__(16) char lds[147456];
  int tid = threadIdx.x;
  int w = tid >> 6, l = tid & 63;
  int a = l & 15, g = l >> 4;
  int qq = w >> 1, sub = w & 1;
  int bx = blockIdx.x;
  int h, batch, qt;
  // XCD-pinning: (batch,h) group <-> XCD (bx%8); each L2 holds its 2MB KV half
  if (split == 2) { h = bx & 1; batch = (bx >> 1) & 3; qt = bx >> 3; }
  else            { h = 0;      batch = (bx >> 1) & 3; qt = ((bx >> 3) << 1) | (bx & 1); }
  int nt = (split == 2) ? 32 : 64;

  uint32_t a7 = a & 7;
  // ---- hoisted LDS byte offsets (v7-verified swizzle forms) ----------------
  // K read: row = sub*32 + n*16 + a (row&7==a7), global granule c5 = j*4+g,
  //         LDS granule = (c5&~7)|((c5^a7)&7); n -> +8192 imm.
  uint32_t kro[8], vro[2], pro[2], pwo[2], kso[4], vso[4];
#pragma unroll
  for (int j = 0; j < 8; ++j) {
    uint32_t c5 = j * 4 + g;
    kro[j] = (uint32_t)(sub * 32 + a) * 512 +
             (((c5 & ~7u) | ((c5 ^ a7) & 7u)) << 4);
  }
  // V read: row = sub*128 + d0*16 + a (row&7==a7), granule = (j2*4+g)^a7 (8/row)
#pragma unroll
  for (int j2 = 0; j2 < 2; ++j2)
    vro[j2] = (uint32_t)(sub * 128 + a) * 128 +
              ((((uint32_t)(j2 * 4 + g)) ^ a7) << 4);
  // P: rows 128x128B at 131072; row = qq*32 + mt*16 + a (row&7==a7)
#pragma unroll
  for (int j2 = 0; j2 < 2; ++j2)
    pro[j2] = 131072u + (uint32_t)(qq * 32 + a) * 128 +
              ((((uint32_t)(j2 * 4 + g)) ^ a7) << 4);
#pragma unroll
  for (int n = 0; n < 2; ++n)
    pwo[n] = 131072u + (uint32_t)(qq * 32 + a) * 128 +
             ((((uint32_t)(sub * 4 + n * 2 + (g >> 1))) ^ a7) << 4) + (g & 1) * 8;
  // stage offsets (source pre-swizzle; LDS dest linear) — verified rounds 1-7
#pragma unroll
  for (int j = 0; j < 4; ++j) {
    uint32_t inst = w * 4 + j, flat = inst * 1024 + l * 16;
    {
      uint32_t row = flat >> 9, c5 = (flat >> 4) & 31;
      kso[j] = row * 512 + (((c5 & ~7u) | ((c5 ^ row) & 7u)) << 4);
    }
    {
      uint32_t row = flat >> 7, c3 = (flat >> 4) & 7;
      vso[j] = row * 128 + ((c3 ^ (row & 7)) << 4);
    }
  }

  // Q fragments: straight layout (B-operand), 32 q-rows of quarter qq
  bf16x8 qfr[2][8];
  {
    const char* qp = (const char*)qs + (size_t)(batch * SEQ + qt * 128) * 512;
#pragma unroll
    for (int mt = 0; mt < 2; ++mt)
#pragma unroll
      for (int j = 0; j < 8; ++j)
        qfr[mt][j] = *(const bf16x8*)(qp + (size_t)(qq * 32 + mt * 16 + a) * 512 +
                                      j * 64 + g * 16);
  }

  f32x4 o[2][8];   // O[32q][128d] (d-half sub), unnormalized partial
  f32x4 lacc[2];   // partial row-sums of P
#pragma unroll
  for (int mt = 0; mt < 2; ++mt) {
    lacc[mt] = (f32x4){0.f, 0.f, 0.f, 0.f};
#pragma unroll
    for (int d0 = 0; d0 < 8; ++d0) o[mt][d0] = (f32x4){0.f, 0.f, 0.f, 0.f};
  }
  const short ob = (short)0x3F80;  // bf16 1.0
  bf16x8 ones = {ob, ob, ob, ob, ob, ob, ob, ob};

  const char* kstp = (const char*)kk + (size_t)batch * SEQ * 512 + (size_t)h * 2048 * 512;
  const char* vstp = vt + (size_t)batch * 64 * 32768 + (size_t)h * 32 * 32768;

  // prologue: stage K(0), V(0) into slot 0
  stage4(kstp, lds, kso, w);
  stage4(vstp, lds + 65536, vso, w);
  kstp += 32768;
  vstp += 32768;

  int tcur = 0;
  int ntHalf = nt >> 1;
  for (int tp = 0; tp < ntHalf; ++tp) {
    TILE(0)
    TILE(1)
  }

  // ---- store partials (unnormalized O + l) --------------------------------
  float* po = (h == 0) ? out : pOB;
  size_t obase = (size_t)(batch * SEQ + qt * 128 + qq * 32) * 256 + sub * 128;
#pragma unroll
  for (int mt = 0; mt < 2; ++mt)
#pragma unroll
    for (int r = 0; r < 4; ++r) {
#pragma unroll
      for (int d0 = 0; d0 < 8; ++d0)
        po[obase + (size_t)(mt * 16 + g * 4 + r) * 256 + d0 * 16 + a] = o[mt][d0][r];
    }
  if (a == 0 && sub == 0) {
#pragma unroll
    for (int mt = 0; mt < 2; ++mt)
#pragma unroll
      for (int r = 0; r < 4; ++r)
        pl[h * 16384 + (batch * 32 + qt) * 128 + qq * 32 + mt * 16 + g * 4 + r] =
            lacc[mt][r];
  }
}

// ---------------- combine: out = (OA + OB) / (lA + lB) ----------------------
__global__ __launch_bounds__(256) void combine_kernel(float* __restrict__ out,
                                                      const float* __restrict__ pOB,
                                                      const float* __restrict__ pl,
                                                      int split) {
  int b = blockIdx.x;            // 16384 = one output row each
  int tid = threadIdx.x;
  int batch = b >> 12;
  int rem = b & 4095;
  int qt = rem >> 7, ql = rem & 127;
  size_t idx = (size_t)b * 256 + tid;
  int li = (batch * 32 + qt) * 128 + ql;
  float lA = pl[li];
  float v;
  if (split == 2) {
    float lB = pl[16384 + li];
    v = (out[idx] + pOB[idx]) / (lA + lB);
  } else {
    v = out[idx] / lA;
  }
  out[idx] = v;
}

extern "C" void kernel_launch(void* const* d_in, const int* in_sizes, int n_in,
                              void* d_out, int out_size, void* d_ws, size_t ws_size,
                              hipStream_t stream) {
  const float* x = (const float*)d_in[0];
  const float* Wq = (const float*)d_in[1];
  const float* bq = (const float*)d_in[2];
  const float* Wk = (const float*)d_in[3];
  const float* bk = (const float*)d_in[4];
  const float* Wv = (const float*)d_in[5];
  const float* bv = (const float*)d_in[6];
  char* ws = (char*)d_ws;
  u16* wt = (u16*)ws;                              // 384KB
  u16* qs = (u16*)(ws + 0x60000);                  // 8MB
  u16* kk = (u16*)(ws + 0x860000);                 // 8MB
  char* vt = ws + 0x1060000;                       // 8MB
  float* pl = (float*)(ws + 0x1860000);            // 128KB
  float* pOB = (float*)(ws + 0x1880000);           // 16MB (split=2 only)
  int split = (ws_size >= 0x2880000ull) ? 2 : 1;
  wt_kernel<<<dim3(768), dim3(256), 0, stream>>>(Wq, Wk, Wv, wt);
  qkv_kernel<<<dim3(256), dim3(256), 0, stream>>>(x, bq, bk, bv, wt, qs, kk, vt);
  attn_kernel<<<dim3(split * 128), dim3(512), 0, stream>>>(qs, kk, vt, (float*)d_out,
                                                           pOB, pl, split);
  combine_kernel<<<dim3(16384), dim3(256), 0, stream>>>((float*)d_out, pOB, pl, split);
}

// Round 12
// 129.133 us; speedup vs baseline: 2.4271x; 1.0178x over previous
//
#include <hip/hip_runtime.h>
#include <stdint.h>

typedef unsigned short u16;
typedef __attribute__((ext_vector_type(4))) float f32x4;
typedef __attribute__((ext_vector_type(8))) short bf16x8;
typedef __attribute__((ext_vector_type(4))) int i32x4;
typedef __attribute__((ext_vector_type(2))) unsigned int u32x2;

#define SEQ 4096
#define DIM 256
// scale = 1/sqrt(256) * log2(e), folded into Wq/bq so softmax uses raw exp2
#define QSCALE 0.09016844f

__device__ __forceinline__ u16 f2bf(float f) {
  union { float f; uint32_t u; } v; v.f = f;
  uint32_t r = (v.u + 0x7FFFu + ((v.u >> 16) & 1u)) >> 16;
  return (u16)r;
}

__device__ __forceinline__ void gload_lds16(const void* g, void* lds) {
  __builtin_amdgcn_global_load_lds(
      (const __attribute__((address_space(1))) uint32_t*)g,
      (__attribute__((address_space(3))) uint32_t*)lds, 16, 0, 0);
}

// ---------------- weight transpose + bf16 cast (scale folded for Wq) --------
__global__ __launch_bounds__(256) void wt_kernel(const float* __restrict__ Wq,
                                                 const float* __restrict__ Wk,
                                                 const float* __restrict__ Wv,
                                                 u16* __restrict__ wt) {
  int b = blockIdx.x;              // 0..767
  int w = b >> 8;                  // which matrix
  int n = b & 255;                 // output column -> wt row
  const float* W = (w == 0) ? Wq : ((w == 1) ? Wk : Wv);
  float scale = (w == 0) ? QSCALE : 1.0f;
  int k = threadIdx.x;
  wt[(w * 256 + n) * 256 + k] = f2bf(W[k * 256 + n] * scale);
}

// ---------------- QKV projection (verified round 1) --------------------------
__global__ __launch_bounds__(256) void qkv_kernel(
    const float* __restrict__ x, const float* __restrict__ bq,
    const float* __restrict__ bk, const float* __restrict__ bv,
    const u16* __restrict__ wt, u16* __restrict__ qs, u16* __restrict__ kk,
    char* __restrict__ vt) {
  __shared__ __align__(16) u16 lds_b[16384];
  __shared__ __align__(16) u16 lds_v[4096];
  int tid = threadIdx.x;
  int w = tid >> 6, l = tid & 63;
  int a = l & 15, g = l >> 4;
  int rowbase = blockIdx.x * 64;

  bf16x8 afr[8];
  {
    int row = rowbase + w * 16 + a;
    const float* xr = x + (size_t)row * 256;
#pragma unroll
    for (int ks = 0; ks < 8; ++ks) {
      int k0 = ks * 32 + g * 8;
      union { bf16x8 s; u16 u[8]; } fr;
#pragma unroll
      for (int i = 0; i < 8; ++i) fr.u[i] = f2bf(xr[k0 + i]);
      afr[ks] = fr.s;
    }
  }

  for (int w3 = 0; w3 < 3; ++w3) {
    const float* bias = (w3 == 0) ? bq : ((w3 == 1) ? bk : bv);
    for (int qn = 0; qn < 4; ++qn) {
      {
        const u16* src = wt + (w3 * 256 + qn * 64) * 256;
        for (int j = 0; j < 8; ++j) {
          uint32_t inst = w * 8 + j;
          uint32_t flat = inst * 1024 + l * 16;
          uint32_t row = flat >> 9;
          uint32_t c5 = (flat >> 4) & 31;
          uint32_t sc = (c5 & ~7u) | ((c5 ^ row) & 7u);
          gload_lds16(src + row * 256 + sc * 8, ((char*)lds_b) + inst * 1024);
        }
      }
      __syncthreads();
      f32x4 acc[4];
#pragma unroll
      for (int n0 = 0; n0 < 4; ++n0) acc[n0] = (f32x4){0.f, 0.f, 0.f, 0.f};
#pragma unroll
      for (int ks = 0; ks < 8; ++ks) {
#pragma unroll
        for (int n0 = 0; n0 < 4; ++n0) {
          uint32_t row = n0 * 16 + a;
          uint32_t c5 = ks * 4 + g;
          uint32_t sc = (c5 & ~7u) | ((c5 ^ row) & 7u);
          bf16x8 bfr = *(const bf16x8*)((const char*)lds_b + row * 512 + sc * 16);
          acc[n0] = __builtin_amdgcn_mfma_f32_16x16x32_bf16(afr[ks], bfr, acc[n0], 0, 0, 0);
        }
      }
      if (w3 < 2) {
        u16* out = (w3 == 0) ? qs : kk;
        float bscale = (w3 == 0) ? QSCALE : 1.0f;
#pragma unroll
        for (int n0 = 0; n0 < 4; ++n0) {
          int col = qn * 64 + n0 * 16 + a;
          float bb = bias[col] * bscale;
#pragma unroll
          for (int r = 0; r < 4; ++r) {
            int row = rowbase + w * 16 + g * 4 + r;
            out[(size_t)row * 256 + col] = f2bf(acc[n0][r] + bb);
          }
        }
      } else {
#pragma unroll
        for (int n0 = 0; n0 < 4; ++n0) {
          int col = qn * 64 + n0 * 16 + a;
          float bb = bias[col];
          int dl = n0 * 16 + a;
#pragma unroll
          for (int r = 0; r < 4; ++r) {
            int m = w * 16 + g * 4 + r;
            uint32_t byteoff =
                (uint32_t)dl * 128 + ((((uint32_t)m >> 3) ^ ((uint32_t)dl & 7)) << 4) + (m & 7) * 2;
            *(u16*)((char*)lds_v + byteoff) = f2bf(acc[n0][r] + bb);
          }
        }
        __syncthreads();
        {
          int dl = tid >> 2;
          size_t base = (size_t)blockIdx.x * 32768 + (size_t)(qn * 64 + dl) * 128;
#pragma unroll
          for (int cc = 0; cc < 2; ++cc) {
            uint32_t c = (tid & 3) + cc * 4;
            i32x4 vd = *(const i32x4*)((const char*)lds_v + dl * 128 + ((c ^ (dl & 7)) << 4));
            *(i32x4*)(vt + base + c * 16) = vd;
          }
        }
      }
      __syncthreads();
    }
  }
}

// ---------------- flash attention v12: v11 + restored 1-barrier pipeline -----
// v11 regressed to 2 barriers/tile: QK(t) and PV(t) serialized (tile 7178cy ~
// VMEM 4096 + LDS 2800 summed). v12 restores the v7 P-dbuf pipeline: per tile
// ONE barrier; PV(t-1) (P/V slot ^1, independent of QK(t)) overlaps QK+stage.
// LDS = 160KB exactly: K dbuf 2x32K | V dbuf 2x32K | P dbuf 2x16K.
// Block = (batch, qt in 32, kv-half h): 128q x 2048kv; partial (O,l) linear
// combine (max-free softmax). Waves (qq = w>>1, sub = w&1).
__device__ __forceinline__ void stage4(const char* src, char* ldsbase,
                                       const uint32_t* so, int w) {
#pragma unroll
  for (int j = 0; j < 4; ++j)
    gload_lds16(src + so[j], ldsbase + (w * 4 + j) * 1024);
}

#define PV_STEP(SLOT)                                                          \
  {                                                                            \
    bf16x8 pfr[2][2];                                                          \
    _Pragma("unroll") for (int mt = 0; mt < 2; ++mt)                           \
    _Pragma("unroll") for (int j2 = 0; j2 < 2; ++j2)                           \
        pfr[mt][j2] = *(const bf16x8*)(lds + (SLOT) * 16384 + pro[j2] + mt * 2048); \
    __builtin_amdgcn_s_setprio(1);                                             \
    _Pragma("unroll") for (int mt = 0; mt < 2; ++mt)                           \
    _Pragma("unroll") for (int j2 = 0; j2 < 2; ++j2)                           \
        lacc[mt] = __builtin_amdgcn_mfma_f32_16x16x32_bf16(pfr[mt][j2], ones,  \
                                                           lacc[mt], 0, 0, 0); \
    _Pragma("unroll") for (int d0 = 0; d0 < 8; ++d0)                           \
    _Pragma("unroll") for (int j2 = 0; j2 < 2; ++j2) {                         \
      bf16x8 vfr = *(const bf16x8*)(lds + 65536 + (SLOT) * 32768 + vro[j2] +   \
                                    d0 * 2048);                                \
      o[0][d0] = __builtin_amdgcn_mfma_f32_16x16x32_bf16(pfr[0][j2], vfr, o[0][d0], 0, 0, 0); \
      o[1][d0] = __builtin_amdgcn_mfma_f32_16x16x32_bf16(pfr[1][j2], vfr, o[1][d0], 0, 0, 0); \
    }                                                                          \
    __builtin_amdgcn_s_setprio(0);                                             \
  }

#define TILE(CUR, DO_PV, DO_K)                                                 \
  {                                                                            \
    asm volatile("s_waitcnt vmcnt(0) lgkmcnt(0)" ::: "memory");                \
    __builtin_amdgcn_s_barrier();                                              \
    __builtin_amdgcn_sched_barrier(0);                                         \
    stage4(vstp, lds + 65536 + (CUR) * 32768, vso, w);   /* V(t) -> slot cur */\
    if (DO_K) stage4(kstp, lds + ((CUR) ^ 1) * 32768, kso, w); /* K(t+1)    */ \
    kstp += 32768;                                                             \
    vstp += 32768;                                                             \
    f32x4 sc[2][2];                                                            \
    _Pragma("unroll") for (int mt = 0; mt < 2; ++mt)                           \
    _Pragma("unroll") for (int n = 0; n < 2; ++n)                              \
        sc[mt][n] = (f32x4){0.f, 0.f, 0.f, 0.f};                               \
    __builtin_amdgcn_s_setprio(1);                                             \
    _Pragma("unroll") for (int n = 0; n < 2; ++n)                              \
    _Pragma("unroll") for (int j = 0; j < 8; ++j) {                            \
      bf16x8 kfr = *(const bf16x8*)(lds + (CUR) * 32768 + kro[j] + n * 8192);  \
      sc[0][n] = __builtin_amdgcn_mfma_f32_16x16x32_bf16(kfr, qfr[0][j], sc[0][n], 0, 0, 0); \
      sc[1][n] = __builtin_amdgcn_mfma_f32_16x16x32_bf16(kfr, qfr[1][j], sc[1][n], 0, 0, 0); \
    }                                                                          \
    __builtin_amdgcn_s_setprio(0);                                             \
    _Pragma("unroll") for (int mt = 0; mt < 2; ++mt)                           \
    _Pragma("unroll") for (int n = 0; n < 2; ++n) {                            \
      float e0 = exp2f(fminf(sc[mt][n][0], 43.f));                             \
      float e1 = exp2f(fminf(sc[mt][n][1], 43.f));                             \
      float e2 = exp2f(fminf(sc[mt][n][2], 43.f));                             \
      float e3 = exp2f(fminf(sc[mt][n][3], 43.f));                             \
      uint32_t p0 = (uint32_t)f2bf(e0) | ((uint32_t)f2bf(e1) << 16);           \
      uint32_t p1 = (uint32_t)f2bf(e2) | ((uint32_t)f2bf(e3) << 16);           \
      u32x2 pk = {p0, p1};                                                     \
      *(u32x2*)(lds + (CUR) * 16384 + pwo[n] + mt * 2048) = pk;                \
    }                                                                          \
    if (DO_PV) PV_STEP((CUR) ^ 1)                                              \
  }

__global__ __launch_bounds__(512, 1) void attn_kernel(
    const u16* __restrict__ qs, const u16* __restrict__ kk,
    const char* __restrict__ vt, float* __restrict__ out,
    float* __restrict__ pOB, float* __restrict__ pl, int split) {
  __shared__ __align__(16) char lds[163840];
  int tid = threadIdx.x;
  int w = tid >> 6, l = tid & 63;
  int a = l & 15, g = l >> 4;
  int qq = w >> 1, sub = w & 1;
  int bx = blockIdx.x;
  int h, batch, qt;
  // XCD-pinning: (batch,h) group <-> XCD (bx%8); each L2 holds its 2MB KV half
  if (split == 2) { h = bx & 1; batch = (bx >> 1) & 3; qt = bx >> 3; }
  else            { h = 0;      batch = (bx >> 1) & 3; qt = ((bx >> 3) << 1) | (bx & 1); }
  int ntHalf = (split == 2) ? 16 : 32;

  uint32_t a7 = a & 7;
  // ---- hoisted LDS byte offsets (v7-verified swizzle forms) ----------------
  uint32_t kro[8], vro[2], pro[2], pwo[2], kso[4], vso[4];
#pragma unroll
  for (int j = 0; j < 8; ++j) {
    uint32_t c5 = j * 4 + g;
    kro[j] = (uint32_t)(sub * 32 + a) * 512 +
             (((c5 & ~7u) | ((c5 ^ a7) & 7u)) << 4);
  }
#pragma unroll
  for (int j2 = 0; j2 < 2; ++j2)
    vro[j2] = (uint32_t)(sub * 128 + a) * 128 +
              ((((uint32_t)(j2 * 4 + g)) ^ a7) << 4);
  // P: 2 slots of 128 rows x 128B at 131072 (+ slot*16384)
#pragma unroll
  for (int j2 = 0; j2 < 2; ++j2)
    pro[j2] = 131072u + (uint32_t)(qq * 32 + a) * 128 +
              ((((uint32_t)(j2 * 4 + g)) ^ a7) << 4);
#pragma unroll
  for (int n = 0; n < 2; ++n)
    pwo[n] = 131072u + (uint32_t)(qq * 32 + a) * 128 +
             ((((uint32_t)(sub * 4 + n * 2 + (g >> 1))) ^ a7) << 4) + (g & 1) * 8;
#pragma unroll
  for (int j = 0; j < 4; ++j) {
    uint32_t inst = w * 4 + j, flat = inst * 1024 + l * 16;
    {
      uint32_t row = flat >> 9, c5 = (flat >> 4) & 31;
      kso[j] = row * 512 + (((c5 & ~7u) | ((c5 ^ row) & 7u)) << 4);
    }
    {
      uint32_t row = flat >> 7, c3 = (flat >> 4) & 7;
      vso[j] = row * 128 + ((c3 ^ (row & 7)) << 4);
    }
  }

  // Q fragments: straight layout (B-operand), 32 q-rows of quarter qq
  bf16x8 qfr[2][8];
  {
    const char* qp = (const char*)qs + (size_t)(batch * SEQ + qt * 128) * 512;
#pragma unroll
    for (int mt = 0; mt < 2; ++mt)
#pragma unroll
      for (int j = 0; j < 8; ++j)
        qfr[mt][j] = *(const bf16x8*)(qp + (size_t)(qq * 32 + mt * 16 + a) * 512 +
                                      j * 64 + g * 16);
  }

  f32x4 o[2][8];   // O[32q][128d] (d-half sub), unnormalized partial
  f32x4 lacc[2];   // partial row-sums of P
#pragma unroll
  for (int mt = 0; mt < 2; ++mt) {
    lacc[mt] = (f32x4){0.f, 0.f, 0.f, 0.f};
#pragma unroll
    for (int d0 = 0; d0 < 8; ++d0) o[mt][d0] = (f32x4){0.f, 0.f, 0.f, 0.f};
  }
  const short ob = (short)0x3F80;  // bf16 1.0
  bf16x8 ones = {ob, ob, ob, ob, ob, ob, ob, ob};

  const char* kstp = (const char*)kk + (size_t)batch * SEQ * 512 + (size_t)h * 2048 * 512;
  const char* vstp = vt + (size_t)batch * 64 * 32768 + (size_t)h * 32 * 32768;

  // prologue: stage K(0) only; V(0) is staged inside tile 0
  stage4(kstp, lds, kso, w);
  kstp += 32768;

  TILE(0, false, true)                       // t = 0
  for (int tp = 0; tp < ntHalf - 1; ++tp) {  // t = 1..nt-2
    TILE(1, true, true)
    TILE(0, true, true)
  }
  TILE(1, true, false)                       // t = nt-1 (no K stage)

  // ---- epilogue: PV(nt-1) from slot 1, then store partials ----------------
  asm volatile("s_waitcnt vmcnt(0) lgkmcnt(0)" ::: "memory");
  __builtin_amdgcn_s_barrier();
  __builtin_amdgcn_sched_barrier(0);
  PV_STEP(1)

  float* po = (h == 0) ? out : pOB;
  size_t obase = (size_t)(batch * SEQ + qt * 128 + qq * 32) * 256 + sub * 128;
#pragma unroll
  for (int mt = 0; mt < 2; ++mt)
#pragma unroll
    for (int r = 0; r < 4; ++r) {
#pragma unroll
      for (int d0 = 0; d0 < 8; ++d0)
        po[obase + (size_t)(mt * 16 + g * 4 + r) * 256 + d0 * 16 + a] = o[mt][d0][r];
    }
  if (a == 0 && sub == 0) {
#pragma unroll
    for (int mt = 0; mt < 2; ++mt)
#pragma unroll
      for (int r = 0; r < 4; ++r)
        pl[h * 16384 + (batch * 32 + qt) * 128 + qq * 32 + mt * 16 + g * 4 + r] =
            lacc[mt][r];
  }
}

// ---------------- combine: out = (OA + OB) / (lA + lB) ----------------------
__global__ __launch_bounds__(256) void combine_kernel(float* __restrict__ out,
                                                      const float* __restrict__ pOB,
                                                      const float* __restrict__ pl,
                                                      int split) {
  int b = blockIdx.x;            // 16384 = one output row each
  int tid = threadIdx.x;
  int batch = b >> 12;
  int rem = b & 4095;
  int qt = rem >> 7, ql = rem & 127;
  size_t idx = (size_t)b * 256 + tid;
  int li = (batch * 32 + qt) * 128 + ql;
  float lA = pl[li];
  float v;
  if (split == 2) {
    float lB = pl[16384 + li];
    v = (out[idx] + pOB[idx]) / (lA + lB);
  } else {
    v = out[idx] / lA;
  }
  out[idx] = v;
}

extern "C" void kernel_launch(void* const* d_in, const int* in_sizes, int n_in,
                              void* d_out, int out_size, void* d_ws, size_t ws_size,
                              hipStream_t stream) {
  const float* x = (const float*)d_in[0];
  const float* Wq = (const float*)d_in[1];
  const float* bq = (const float*)d_in[2];
  const float* Wk = (const float*)d_in[3];
  const float* bk = (const float*)d_in[4];
  const float* Wv = (const float*)d_in[5];
  const float* bv = (const float*)d_in[6];
  char* ws = (char*)d_ws;
  u16* wt = (u16*)ws;                              // 384KB
  u16* qs = (u16*)(ws + 0x60000);                  // 8MB
  u16* kk = (u16*)(ws + 0x860000);                 // 8MB
  char* vt = ws + 0x1060000;                       // 8MB
  float* pl = (float*)(ws + 0x1860000);            // 128KB
  float* pOB = (float*)(ws + 0x1880000);           // 16MB (split=2 only)
  int split = (ws_size >= 0x2880000ull) ? 2 : 1;
  wt_kernel<<<dim3(768), dim3(256), 0, stream>>>(Wq, Wk, Wv, wt);
  qkv_kernel<<<dim3(256), dim3(256), 0, stream>>>(x, bq, bk, bv, wt, qs, kk, vt);
  attn_kernel<<<dim3(split * 128), dim3(512), 0, stream>>>(qs, kk, vt, (float*)d_out,
                                                           pOB, pl, split);
  combine_kernel<<<dim3(16384), dim3(256), 0, stream>>>((float*)d_out, pOB, pl, split);
}